// Round 5
// baseline (69.079 us; speedup 1.0000x reference)
//
#include <hip/hip_runtime.h>

// Problem constants (fixed by the reference)
#define C_TOT 160            // combined rows (entries from all 160 feed output)
#define C_USE 128            // lv rows consumable: wids[c] in [0,128)
#define R_    64
#define D_    4096
#define B_TOK 256
#define NENT  (C_TOT * R_)   // 10240 scatter entries
#define KS    16             // k-split for stage 1
#define KSPAN (D_ / KS)      // 256 floats per slice
#define LVN   (C_USE * R_)   // 8192 lv entries
#define NCAP  256            // per-token entry capacity (mean 40)
#define CH    2              // D-chunks per token in stage 2

typedef float float4v __attribute__((ext_vector_type(4)));

// Scratch as device globals (capture-safe, rewritten every call).
__device__ float g_lvp[KS][LVN];   // stage-1 partials, 512 KB
__device__ float g_lv[LVN];        // reduced lv table, 32 KB

// ---------------------------------------------------------------------------
// S1: lv partials for c in [0,128). grid = C_USE*KS = 2048 blocks, 256 thr.
// x token rows staged in LDS (coalesced), XOR-swizzled so the per-lane
// row-reads are bank-uniform. A reads stay lane-over-r 256B-coalesced.
// ---------------------------------------------------------------------------
__global__ __launch_bounds__(256) void s1(const float* __restrict__ A,
                                          const float* __restrict__ x,
                                          const int* __restrict__ xids,
                                          const int* __restrict__ wids) {
  const int b    = blockIdx.x;
  const int c    = b >> 4;            // lv row, c < 128
  const int ks   = b & (KS - 1);      // k-slice
  const int tid  = threadIdx.x;
  const int lane = tid & 63;
  const int wv   = tid >> 6;

  __shared__ int    s_tok[64];
  __shared__ float4v xs[64][64];      // [row-slot][swizzled float4 col] 64 KB
  __shared__ float  part[4][64];

  if (tid < 64) s_tok[tid] = xids[c * R_ + tid];
  __syncthreads();

  // Stage: wave wv loads rows {4*rep + wv}; lanes sweep the 64 float4 cols.
  #pragma unroll 4
  for (int rep = 0; rep < 16; ++rep) {
    const int row = rep * 4 + wv;
    const float* __restrict__ src =
        x + (size_t)s_tok[row] * D_ + ks * KSPAN + lane * 4;
    xs[row][lane ^ (row & 7)] = *reinterpret_cast<const float4v*>(src);
  }
  __syncthreads();

  // Compute: lane = r reads its own LDS row; wave wv covers k-quarter.
  const int r = lane;
  const int w = wids[c];
  const float* __restrict__ acol =
      A + (size_t)w * (D_ * R_) + (size_t)(ks * KSPAN) * R_ + r;

  float acc = 0.f;
  #pragma unroll 4
  for (int jj = 0; jj < 16; ++jj) {
    const int j = wv * 16 + jj;                 // logical float4 col
    const float4v xv = xs[r][j ^ (r & 7)];
    const int k = j * 4;
    acc = fmaf(xv[0], acol[(size_t)(k + 0) * R_], acc);
    acc = fmaf(xv[1], acol[(size_t)(k + 1) * R_], acc);
    acc = fmaf(xv[2], acol[(size_t)(k + 2) * R_], acc);
    acc = fmaf(xv[3], acol[(size_t)(k + 3) * R_], acc);
  }

  part[wv][r] = acc;
  __syncthreads();
  if (tid < 64)
    g_lvp[ks][c * R_ + tid] =
        part[0][tid] + part[1][tid] + part[2][tid] + part[3][tid];
}

// ---------------------------------------------------------------------------
// S1R: collapse the KS partials -> g_lv. grid = LVN/256 = 32 blocks.
// ---------------------------------------------------------------------------
__global__ __launch_bounds__(256) void s1r() {
  const int i = blockIdx.x * 256 + threadIdx.x;
  float s = 0.f;
  #pragma unroll
  for (int p = 0; p < KS; ++p) s += g_lvp[p][i];
  g_lv[i] = s;
}

// ---------------------------------------------------------------------------
// S2: per-token gather. grid = B_TOK*CH = 512 blocks, 256 threads.
// Each block: one token, D/CH = 2048 floats (8 contiguous floats / thread,
// two independent FMA chains). Entry list via parallel filter over xids.
// ---------------------------------------------------------------------------
__global__ __launch_bounds__(256) void s2(const float* __restrict__ Bm,
                                          const int* __restrict__ xids,
                                          const int* __restrict__ wids,
                                          float* __restrict__ out) {
  const int t   = blockIdx.x >> 1;
  const int ch  = blockIdx.x & (CH - 1);
  const int tid = threadIdx.x;
  const int d0  = ch * (D_ / CH) + tid * 8;

  __shared__ int   s_n;
  __shared__ int   s_idx[NCAP];
  __shared__ float s_cf[NCAP];
  if (tid == 0) s_n = 0;
  __syncthreads();
  for (int i = tid; i < NENT; i += 256) {
    if (xids[i] == t) {
      const int p = atomicAdd(&s_n, 1);
      if (p < NCAP) s_idx[p] = wids[i >> 6] * R_ + (i & 63);  // lv/B row index
    }
  }
  __syncthreads();
  const int n = (s_n < NCAP) ? s_n : NCAP;
  if (tid < n) s_cf[tid] = g_lv[s_idx[tid]];
  __syncthreads();

  float4v a0, a1;
  a0[0] = a0[1] = a0[2] = a0[3] = 0.f;
  a1[0] = a1[1] = a1[2] = a1[3] = 0.f;

  #pragma unroll 2
  for (int j = 0; j < n; ++j) {
    const int   idx = s_idx[j];
    const float cf  = s_cf[j];
    const float* __restrict__ brow = Bm + (size_t)idx * D_ + d0;
    const float4v b0 = *reinterpret_cast<const float4v*>(brow);
    const float4v b1 = *reinterpret_cast<const float4v*>(brow + 4);
    a0[0] = fmaf(cf, b0[0], a0[0]);
    a0[1] = fmaf(cf, b0[1], a0[1]);
    a0[2] = fmaf(cf, b0[2], a0[2]);
    a0[3] = fmaf(cf, b0[3], a0[3]);
    a1[0] = fmaf(cf, b1[0], a1[0]);
    a1[1] = fmaf(cf, b1[1], a1[1]);
    a1[2] = fmaf(cf, b1[2], a1[2]);
    a1[3] = fmaf(cf, b1[3], a1[3]);
  }

  float4v o0, o1;
  o0[0] = 2.0f * a0[0]; o0[1] = 2.0f * a0[1];
  o0[2] = 2.0f * a0[2]; o0[3] = 2.0f * a0[3];
  o1[0] = 2.0f * a1[0]; o1[1] = 2.0f * a1[1];
  o1[2] = 2.0f * a1[2]; o1[3] = 2.0f * a1[3];
  float* __restrict__ orow = out + (size_t)t * D_ + d0;
  *reinterpret_cast<float4v*>(orow)     = o0;
  *reinterpret_cast<float4v*>(orow + 4) = o1;
}

// ---------------------------------------------------------------------------
extern "C" void kernel_launch(void* const* d_in, const int* in_sizes, int n_in,
                              void* d_out, int out_size, void* d_ws, size_t ws_size,
                              hipStream_t stream) {
  const float* lora_A = (const float*)d_in[0];
  const float* lora_B = (const float*)d_in[1];
  const float* x      = (const float*)d_in[2];
  const int* xids = (const int*)d_in[3];
  const int* wids = (const int*)d_in[4];
  float* out = (float*)d_out;

  hipLaunchKernelGGL(s1, dim3(C_USE * KS), dim3(256), 0, stream,
                     lora_A, x, xids, wids);
  hipLaunchKernelGGL(s1r, dim3(LVN / 256), dim3(256), 0, stream);
  hipLaunchKernelGGL(s2, dim3(B_TOK * CH), dim3(256), 0, stream,
                     lora_B, xids, wids, out);
}

// Round 6
// 67.663 us; speedup vs baseline: 1.0209x; 1.0209x over previous
//
#include <hip/hip_runtime.h>

// Problem constants (fixed by the reference)
#define C_TOT 160            // combined rows
#define C_ROW 128            // lv row space: wids values lie in [0,128)
#define R_    64
#define D_    4096
#define B_TOK 256
#define NENT  (C_TOT * R_)   // 10240 scatter entries
#define KS    8              // k-split for stage 1
#define KSPAN (D_ / KS)      // 512 floats per slice
#define LVN   (C_ROW * R_)   // 8192 lv entries
#define NCAP  256            // per-token entry capacity (mean 40)
#define CH    4              // D-chunks per token in stage 2

typedef float float4v __attribute__((ext_vector_type(4)));

// Scratch as device globals (capture-safe, rewritten every call).
__device__ float g_lvp[KS][LVN];   // stage-1 partials, 256 KB
__device__ int   g_need[C_ROW];    // needed lv rows, sorted by adapter id
__device__ int   g_nneed;

// ---------------------------------------------------------------------------
// PREP: needed lv rows = unique(wids) (~91 of 128). Sort them by their
// adapter wids[w] so S1 blocks sharing an A-slice are grid-adjacent
// (concurrent dispatch -> L2/L3 dedupes the duplicate slice reads).
// ---------------------------------------------------------------------------
__global__ __launch_bounds__(256) void k_prep(const int* __restrict__ wids) {
  __shared__ int isN[C_ROW];
  __shared__ int cnt[C_ROW];
  __shared__ int cur[C_ROW];
  const int tid = threadIdx.x;
  if (tid < C_ROW) { isN[tid] = 0; cnt[tid] = 0; }
  __syncthreads();
  if (tid < C_TOT) atomicExch(&isN[wids[tid]], 1);
  __syncthreads();
  if (tid < C_ROW && isN[tid]) atomicAdd(&cnt[wids[tid]], 1);
  __syncthreads();
  if (tid == 0) {
    int s = 0;
    for (int a = 0; a < C_ROW; ++a) { cur[a] = s; s += cnt[a]; }
    g_nneed = s;
  }
  __syncthreads();
  if (tid < C_ROW && isN[tid]) {
    const int pos = atomicAdd(&cur[wids[tid]], 1);
    g_need[pos] = tid;
  }
}

// ---------------------------------------------------------------------------
// S1: lv partials for needed rows only. grid = C_ROW*KS = 1024 blocks
// (surplus blocks exit), 256 thr. lane = r -> A reads 256B wave-coalesced;
// x row read as float4 (gather, L2/L3-served).
// ---------------------------------------------------------------------------
__global__ __launch_bounds__(256) void s1(const float* __restrict__ A,
                                          const float* __restrict__ x,
                                          const int* __restrict__ xids,
                                          const int* __restrict__ wids) {
  const int i = blockIdx.x >> 3;       // needed-row slot
  if (i >= g_nneed) return;
  const int ks  = blockIdx.x & (KS - 1);
  const int tid = threadIdx.x;
  const int r   = tid & 63;
  const int wv  = tid >> 6;            // wave: quarter of this k-slice
  const int w   = g_need[i];           // lv row
  const int a   = wids[w];             // adapter
  const int tok = xids[w * R_ + r];

  const float* __restrict__ xrow = x + (size_t)tok * D_;
  const float* __restrict__ acol = A + (size_t)a * (D_ * R_) + r;

  const int k0 = ks * KSPAN + wv * (KSPAN / 4);   // 128 k's per wave
  float acc = 0.f;
  #pragma unroll 4
  for (int k = k0; k < k0 + (KSPAN / 4); k += 4) {
    const float4v xv = *reinterpret_cast<const float4v*>(xrow + k);
    acc = fmaf(xv[0], acol[(size_t)(k + 0) * R_], acc);
    acc = fmaf(xv[1], acol[(size_t)(k + 1) * R_], acc);
    acc = fmaf(xv[2], acol[(size_t)(k + 2) * R_], acc);
    acc = fmaf(xv[3], acol[(size_t)(k + 3) * R_], acc);
  }

  __shared__ float part[4][64];
  part[wv][r] = acc;
  __syncthreads();
  if (tid < 64)
    g_lvp[ks][w * R_ + tid] =
        part[0][tid] + part[1][tid] + part[2][tid] + part[3][tid];
}

// ---------------------------------------------------------------------------
// S2: per-token gather. grid = B_TOK*CH = 1024 blocks, 256 threads.
// Each block: one token, D/CH = 1024 floats (float4 per thread).
// Entry list via parallel filter over xids; cf sums the KS partials once
// per entry (uniform loads by the filler thread).
// ---------------------------------------------------------------------------
__global__ __launch_bounds__(256) void s2(const float* __restrict__ Bm,
                                          const int* __restrict__ xids,
                                          const int* __restrict__ wids,
                                          float* __restrict__ out) {
  const int t   = blockIdx.x >> 2;
  const int ch  = blockIdx.x & (CH - 1);
  const int tid = threadIdx.x;
  const int d0  = ch * (D_ / CH) + tid * 4;

  __shared__ int   s_n;
  __shared__ int   s_idx[NCAP];
  __shared__ float s_cf[NCAP];
  if (tid == 0) s_n = 0;
  __syncthreads();
  for (int i = tid; i < NENT; i += 256) {
    if (xids[i] == t) {
      const int p = atomicAdd(&s_n, 1);
      if (p < NCAP) s_idx[p] = wids[i >> 6] * R_ + (i & 63);  // lv/B row index
    }
  }
  __syncthreads();
  const int n = (s_n < NCAP) ? s_n : NCAP;
  if (tid < n) {
    const int idx = s_idx[tid];
    float cf = 0.f;
    #pragma unroll
    for (int p = 0; p < KS; ++p) cf += g_lvp[p][idx];
    s_cf[tid] = cf;
  }
  __syncthreads();

  float4v acc;
  acc[0] = acc[1] = acc[2] = acc[3] = 0.f;

  #pragma unroll 2
  for (int j = 0; j < n; ++j) {
    const int   idx = s_idx[j];
    const float cf  = s_cf[j];
    const float4v bv =
        *reinterpret_cast<const float4v*>(Bm + (size_t)idx * D_ + d0);
    acc[0] = fmaf(cf, bv[0], acc[0]);
    acc[1] = fmaf(cf, bv[1], acc[1]);
    acc[2] = fmaf(cf, bv[2], acc[2]);
    acc[3] = fmaf(cf, bv[3], acc[3]);
  }

  float4v o;
  o[0] = 2.0f * acc[0]; o[1] = 2.0f * acc[1];
  o[2] = 2.0f * acc[2]; o[3] = 2.0f * acc[3];
  *reinterpret_cast<float4v*>(out + (size_t)t * D_ + d0) = o;
}

// ---------------------------------------------------------------------------
extern "C" void kernel_launch(void* const* d_in, const int* in_sizes, int n_in,
                              void* d_out, int out_size, void* d_ws, size_t ws_size,
                              hipStream_t stream) {
  const float* lora_A = (const float*)d_in[0];
  const float* lora_B = (const float*)d_in[1];
  const float* x      = (const float*)d_in[2];
  const int* xids = (const int*)d_in[3];
  const int* wids = (const int*)d_in[4];
  float* out = (float*)d_out;

  hipLaunchKernelGGL(k_prep, dim3(1), dim3(256), 0, stream, wids);
  hipLaunchKernelGGL(s1, dim3(C_ROW * KS), dim3(256), 0, stream,
                     lora_A, x, xids, wids);
  hipLaunchKernelGGL(s2, dim3(B_TOK * CH), dim3(256), 0, stream,
                     lora_B, xids, wids, out);
}